// Round 7
// baseline (27.274 us; speedup 1.0000x reference)
//
#include <hip/hip_runtime.h>
#include <stdint.h>

// Forward kinematics, 24-joint chain, 4 lanes/sample + Kogge-Stone scan.
// Round-7: fully wave-local, ZERO __syncthreads.
//  - input staged via __builtin_amdgcn_global_load_lds (16B/lane, linear LDS,
//    no VGPR round-trip; compiler never auto-emits this)
//  - wave w loads/computes/stores only its own 16 samples; out-staging reuses
//    the first half of the wave's OWN input region (reads complete by then)
//  - LDS linear stride 36 float4: compute-read banks (4s+seg+3p+q)%8 cover
//    all 8 b128 start-slots -> uniform 8 words/bank = HW minimum, no conflicts
// Roofline: 75.5MB in + 37.7MB out ~= 18us @ 6.3TB/s copy ceiling.

#define N_JOINTS 24
#define SPB 32          // samples per block
#define BT  128         // threads per block (2 independent waves)

#define GLOAD_LDS16(gptr, lptr)                                            \
  __builtin_amdgcn_global_load_lds(                                        \
      (const __attribute__((address_space(1))) uint32_t*)(gptr),           \
      (__attribute__((address_space(3))) uint32_t*)(lptr), 16, 0, 0)

__global__ __launch_bounds__(BT, 4) void fk_kernel(
    const float4* __restrict__ ain,   // angles as float4: [N*36]
    const float*  __restrict__ xyz,   // [24][3]
    float4* __restrict__ aout)        // out as float4: [N*18]
{
    __shared__ float4 s_buf[SPB * 36];        // 18432 B linear; reused for out
    __shared__ float  s_t[2][N_JOINTS * 3];   // per-wave copy (barrier-free)

    const int tid  = threadIdx.x;
    const int w    = tid >> 6;        // wave 0/1
    const int lane = tid & 63;

    // ---- per-wave local translations (joint 0 uses xyz0[0] raw) ----
    if (lane < N_JOINTS) {
        float x = xyz[lane * 3 + 0];
        float y = xyz[lane * 3 + 1];
        float z = xyz[lane * 3 + 2];
        if (lane > 0) {
            x -= xyz[lane * 3 - 3];
            y -= xyz[lane * 3 - 2];
            z -= xyz[lane * 3 - 1];
        }
        s_t[w][lane * 3 + 0] = x;
        s_t[w][lane * 3 + 1] = y;
        s_t[w][lane * 3 + 2] = z;
    }

    // ---- wave-local input stage: wave w -> its 16 samples = 576 float4 ----
    // dest is wave-uniform base + lane*16 (HW-defined); global addr per-lane.
    const size_t gbase = (size_t)blockIdx.x * (SPB * 36) + (size_t)(w * 576 + lane);
    #pragma unroll
    for (int it = 0; it < 9; ++it) {
        GLOAD_LDS16(ain + gbase + it * 64, &s_buf[w * 576 + it * 64]);
    }
    asm volatile("s_waitcnt vmcnt(0) lgkmcnt(0)" ::: "memory");
    __builtin_amdgcn_sched_barrier(0);

    // ---- Compute: lane group of 4 per sample ----
    const int s   = tid >> 2;    // 0..31 (wave 0: 0-15, wave 1: 16-31)
    const int seg = tid & 3;     // joints [seg*6, seg*6+6)
    const float4* __restrict__ row = &s_buf[s * 36 + seg * 9];

    float R[9], t[3];    // segment-local cumulative transform
    float o[18];         // 6 segment-local translations

    #pragma unroll
    for (int p = 0; p < 3; ++p) {           // 2 joints per float4-triple
        const float4 v0 = row[p * 3 + 0];
        const float4 v1 = row[p * 3 + 1];
        const float4 v2 = row[p * 3 + 2];
        float d6[12];
        d6[0] = v0.x; d6[1] = v0.y; d6[2]  = v0.z; d6[3]  = v0.w;
        d6[4] = v1.x; d6[5] = v1.y; d6[6]  = v1.z; d6[7]  = v1.w;
        d6[8] = v2.x; d6[9] = v2.y; d6[10] = v2.z; d6[11] = v2.w;

        #pragma unroll
        for (int h = 0; h < 2; ++h) {
            const int jl = p * 2 + h;       // 0..5 within segment
            const int j  = seg * 6 + jl;    // global joint id
            const float a1x = d6[h * 6 + 0], a1y = d6[h * 6 + 1], a1z = d6[h * 6 + 2];
            const float a2x = d6[h * 6 + 3], a2y = d6[h * 6 + 4], a2z = d6[h * 6 + 5];

            // Gram-Schmidt (Zhou 6D -> rows b1,b2,b3); rsqrtf -> v_rsq_f32
            const float inv1 = rsqrtf(a1x * a1x + a1y * a1y + a1z * a1z);
            const float b1x = a1x * inv1, b1y = a1y * inv1, b1z = a1z * inv1;
            const float dd = b1x * a2x + b1y * a2y + b1z * a2z;
            float b2x = a2x - dd * b1x, b2y = a2y - dd * b1y, b2z = a2z - dd * b1z;
            const float inv2 = rsqrtf(b2x * b2x + b2y * b2y + b2z * b2z);
            b2x *= inv2; b2y *= inv2; b2z *= inv2;
            const float b3x = b1y * b2z - b1z * b2y;
            const float b3y = b1z * b2x - b1x * b2z;
            const float b3z = b1x * b2y - b1y * b2x;
            const float Rj[9] = { b1x, b1y, b1z,  b2x, b2y, b2z,  b3x, b3y, b3z };

            const float tx = s_t[w][j * 3 + 0], ty = s_t[w][j * 3 + 1], tz = s_t[w][j * 3 + 2];
            const float tlx = Rj[0] * tx + Rj[1] * ty + Rj[2] * tz;
            const float tly = Rj[3] * tx + Rj[4] * ty + Rj[5] * tz;
            const float tlz = Rj[6] * tx + Rj[7] * ty + Rj[8] * tz;

            if (jl == 0) {
                #pragma unroll
                for (int k = 0; k < 9; ++k) R[k] = Rj[k];
                t[0] = tlx; t[1] = tly; t[2] = tlz;
            } else {
                t[0] += R[0] * tlx + R[1] * tly + R[2] * tlz;
                t[1] += R[3] * tlx + R[4] * tly + R[5] * tlz;
                t[2] += R[6] * tlx + R[7] * tly + R[8] * tlz;
                float Nn[9];
                #pragma unroll
                for (int r2 = 0; r2 < 3; ++r2)
                    #pragma unroll
                    for (int c = 0; c < 3; ++c)
                        Nn[r2 * 3 + c] = R[r2 * 3 + 0] * Rj[0 * 3 + c]
                                       + R[r2 * 3 + 1] * Rj[1 * 3 + c]
                                       + R[r2 * 3 + 2] * Rj[2 * 3 + c];
                #pragma unroll
                for (int k = 0; k < 9; ++k) R[k] = Nn[k];
            }
            o[jl * 3 + 0] = t[0];
            o[jl * 3 + 1] = t[1];
            o[jl * 3 + 2] = t[2];
        }
    }

    // ---- Kogge-Stone inclusive scan over the 4 lanes of a sample ----
    #pragma unroll
    for (int d = 1; d <= 2; d *= 2) {
        float LR[9], Lt[3];
        #pragma unroll
        for (int k = 0; k < 9; ++k) LR[k] = __shfl_up(R[k], (unsigned)d);
        #pragma unroll
        for (int c = 0; c < 3; ++c) Lt[c] = __shfl_up(t[c], (unsigned)d);
        if (seg >= d) {
            float nt0 = Lt[0] + LR[0] * t[0] + LR[1] * t[1] + LR[2] * t[2];
            float nt1 = Lt[1] + LR[3] * t[0] + LR[4] * t[1] + LR[5] * t[2];
            float nt2 = Lt[2] + LR[6] * t[0] + LR[7] * t[1] + LR[8] * t[2];
            float Nn[9];
            #pragma unroll
            for (int r2 = 0; r2 < 3; ++r2)
                #pragma unroll
                for (int c = 0; c < 3; ++c)
                    Nn[r2 * 3 + c] = LR[r2 * 3 + 0] * R[0 * 3 + c]
                                   + LR[r2 * 3 + 1] * R[1 * 3 + c]
                                   + LR[r2 * 3 + 2] * R[2 * 3 + c];
            #pragma unroll
            for (int k = 0; k < 9; ++k) R[k] = Nn[k];
            t[0] = nt0; t[1] = nt1; t[2] = nt2;
        }
    }

    // Exclusive prefix = inclusive of lane-1 (identity for seg 0; cross-sample
    // garbage at seg==0 fully overwritten).
    float ER[9], Et[3];
    #pragma unroll
    for (int k = 0; k < 9; ++k) ER[k] = __shfl_up(R[k], 1u);
    #pragma unroll
    for (int c = 0; c < 3; ++c) Et[c] = __shfl_up(t[c], 1u);
    if (seg == 0) {
        ER[0] = 1.f; ER[1] = 0.f; ER[2] = 0.f;
        ER[3] = 0.f; ER[4] = 1.f; ER[5] = 0.f;
        ER[6] = 0.f; ER[7] = 0.f; ER[8] = 1.f;
        Et[0] = 0.f; Et[1] = 0.f; Et[2] = 0.f;
    }

    // Fixup: global translation = Et + ER @ local.
    #pragma unroll
    for (int k = 0; k < 6; ++k) {
        const float ox = o[3 * k + 0], oy = o[3 * k + 1], oz = o[3 * k + 2];
        o[3 * k + 0] = Et[0] + ER[0] * ox + ER[1] * oy + ER[2] * oz;
        o[3 * k + 1] = Et[1] + ER[3] * ox + ER[4] * oy + ER[5] * oz;
        o[3 * k + 2] = Et[2] + ER[6] * ox + ER[7] * oy + ER[8] * oz;
    }

    // ---- Wave-local out-stage into first half of the wave's OWN input
    // region (float4 [w*576, w*576+288)): input reads complete (data dep +
    // per-wave in-order DS), no barrier needed.
    float2* ob = reinterpret_cast<float2*>(s_buf);
    #pragma unroll
    for (int q = 0; q < 9; ++q) {
        float2 v; v.x = o[2 * q + 0]; v.y = o[2 * q + 1];
        ob[(size_t)w * 1152 + lane * 9 + q] = v;   // lane*9 % 16 covers all -> 2-way max
    }

    // ---- Wave-local coalesced store: 288 float4 per wave ----
    const size_t out_base = (size_t)blockIdx.x * (SPB * 18) + (size_t)(w * 288);
    #pragma unroll
    for (int it = 0; it < 4; ++it)
        aout[out_base + lane + 64 * it] = s_buf[w * 576 + lane + 64 * it];
    if (lane < 32)
        aout[out_base + 256 + lane] = s_buf[w * 576 + 256 + lane];
}

extern "C" void kernel_launch(void* const* d_in, const int* in_sizes, int n_in,
                              void* d_out, int out_size, void* d_ws, size_t ws_size,
                              hipStream_t stream) {
    const float* angles = (const float*)d_in[0];   // [N][24][6] f32
    const float* xyz    = (const float*)d_in[1];   // [1][24][3] f32
    float* out = (float*)d_out;

    const int N = in_sizes[0] / (N_JOINTS * 6);    // 131072; divisible by 32
    const int grid = N / SPB;                       // 4096 blocks
    fk_kernel<<<grid, BT, 0, stream>>>(
        reinterpret_cast<const float4*>(angles), xyz,
        reinterpret_cast<float4*>(out));
}